// Round 17
// baseline (733.154 us; speedup 1.0000x reference)
//
#include <hip/hip_runtime.h>
#include <hip/hip_bf16.h>
#include <hip/hip_cooperative_groups.h>
#include <stdint.h>

namespace cg = cooperative_groups;

typedef unsigned short u16;
typedef __attribute__((ext_vector_type(8))) __bf16 bf16x8;
typedef __attribute__((ext_vector_type(4))) float f32x4;

#define BN_EPS 1e-5f
#define MROWS 65536
#define INV_M (1.0f / 65536.0f)
#define NREP 16
// zero region: s0rep[16*512] | s1sum/s1sq[1024] | s2sum/s2sq[1024] | maxbuf[32768]
#define ZWORDS (16 * 512 + 2048 + 32768)

__device__ __forceinline__ u16 f2bf(float f) {
  unsigned u = __builtin_bit_cast(unsigned, f);
  unsigned r = (u + 0x7FFFu + ((u >> 16) & 1u)) >> 16;
  return (u16)r;
}

#define GLDS16(gp, lp) __builtin_amdgcn_global_load_lds( \
    (__attribute__((address_space(1))) void*)(void*)(gp), \
    (__attribute__((address_space(3))) void*)(lp), 16, 0, 0)

// ---------------- GEMM tile (r13 body verbatim, tile index as parameter) ----------------
template <int KDIM, int NDIM, bool RELU, bool DOMAX>
__device__ __forceinline__
void gemm_tile(const u16* __restrict__ A, const u16* __restrict__ B,
               const float* __restrict__ cp, u16* __restrict__ Y,
               float* __restrict__ osum, float* __restrict__ osq,
               unsigned* __restrict__ maxbuf, int tile, u16* lds, int t) {
  constexpr int NK = KDIM >> 5;
  const int w = t >> 6, l = t & 63;
  const int lr = l & 15, lk = l >> 4;
  const int wm = w >> 2, wn = w & 3;
  constexpr int TILES_N = NDIM >> 8;
  const int tm0 = (tile / TILES_N) << 8;
  const int tn0 = (tile % TILES_N) << 8;

  // mega-kernel tile entry: drain vmem (epilogue stores/atomics of prior tile,
  // so prologue vmcnt(8) counts ONLY its own stages) and protect LDS reuse.
  asm volatile("s_waitcnt vmcnt(0)" ::: "memory");
  __syncthreads();

  const int srow = t >> 2;
  const int scol = (((t & 3) ^ ((t >> 3) & 3)) << 3);
  const u16* Ag = A + (size_t)(tm0 + srow) * KDIM + scol;
  const u16* Bg = B + (size_t)(tn0 + srow) * KDIM + scol;
  u16* const ldsA = lds;
  u16* const ldsB = lds + 4 * 8192;

#define STAGE_A(slot_, kt_) do { \
    GLDS16(Ag + (kt_) * 32, ldsA + (slot_) * 8192 + t * 8); \
    GLDS16(Ag + (size_t)128 * KDIM + (kt_) * 32, ldsA + (slot_) * 8192 + 4096 + t * 8); \
  } while (0)
#define STAGE_B(slot_, kt_) do { \
    GLDS16(Bg + (kt_) * 32, ldsB + (slot_) * 8192 + t * 8); \
    GLDS16(Bg + (size_t)128 * KDIM + (kt_) * 32, ldsB + (slot_) * 8192 + 4096 + t * 8); \
  } while (0)

  const int pc = (lk ^ ((lr >> 1) & 3)) * 8;
  const int rba = wm * 128 + lr;
  const int rbb = wn * 64 + lr;

  f32x4 acc[8][4] = {};

  STAGE_A(0, 0); STAGE_B(0, 0);
  STAGE_A(1, 1); STAGE_B(1, 1);
  STAGE_A(2, 2); STAGE_B(2, 2);
  asm volatile("s_waitcnt vmcnt(8)" ::: "memory");
  __builtin_amdgcn_s_barrier();

#pragma unroll
  for (int T = 0; T < NK; ++T) {
    const int sl = T & 3;
    const u16* la = ldsA + sl * 8192;
    const u16* lb = ldsB + sl * 8192;
    bf16x8 af[4], bf[4];
#pragma unroll
    for (int n = 0; n < 4; ++n)
      bf[n] = *(const bf16x8*)(lb + (rbb + n * 16) * 32 + pc);
#pragma unroll
    for (int j = 0; j < 4; ++j)
      af[j] = *(const bf16x8*)(la + (rba + j * 16) * 32 + pc);
    if (T + 3 < NK) STAGE_A((T + 3) & 3, T + 3);
    __builtin_amdgcn_s_barrier();
    __builtin_amdgcn_s_setprio(1);
#pragma unroll
    for (int j = 0; j < 4; ++j)
#pragma unroll
      for (int n = 0; n < 4; ++n)
        acc[j][n] = __builtin_amdgcn_mfma_f32_16x16x32_bf16(af[j], bf[n], acc[j][n], 0, 0, 0);
    __builtin_amdgcn_s_setprio(0);
#pragma unroll
    for (int j = 0; j < 4; ++j)
      af[j] = *(const bf16x8*)(la + (rba + 64 + j * 16) * 32 + pc);
    if (T + 3 < NK) STAGE_B((T + 3) & 3, T + 3);
    if (T < NK - 3)       asm volatile("s_waitcnt vmcnt(8)" ::: "memory");
    else if (T == NK - 3) asm volatile("s_waitcnt vmcnt(4)" ::: "memory");
    else if (T == NK - 2) asm volatile("s_waitcnt vmcnt(0)" ::: "memory");
    __builtin_amdgcn_s_barrier();
    __builtin_amdgcn_s_setprio(1);
#pragma unroll
    for (int j = 0; j < 4; ++j)
#pragma unroll
      for (int n = 0; n < 4; ++n)
        acc[4 + j][n] = __builtin_amdgcn_mfma_f32_16x16x32_bf16(af[j], bf[n], acc[4 + j][n], 0, 0, 0);
    __builtin_amdgcn_s_setprio(0);
  }
#undef STAGE_A
#undef STAGE_B

  if (!DOMAX) {
    float cs[4] = {}, cq[4] = {};
#pragma unroll
    for (int n = 0; n < 4; ++n) {
      const int gcol = tn0 + wn * 64 + n * 16 + lr;
      const float cb = cp[gcol];
#pragma unroll
      for (int m = 0; m < 8; ++m) {
        const int grow = tm0 + wm * 128 + m * 16 + lk * 4;
#pragma unroll
        for (int r = 0; r < 4; ++r) {
          float v = acc[m][n][r] + cb;
          if (RELU) v = fmaxf(v, 0.f);
          Y[(size_t)(grow + r) * NDIM + gcol] = f2bf(v);
          cs[n] += v;
          cq[n] += v * v;
        }
      }
    }
    if (RELU) {
#pragma unroll
      for (int n = 0; n < 4; ++n) {
        cs[n] += __shfl_xor(cs[n], 16, 64);
        cs[n] += __shfl_xor(cs[n], 32, 64);
        cq[n] += __shfl_xor(cq[n], 16, 64);
        cq[n] += __shfl_xor(cq[n], 32, 64);
      }
      float* sred = (float*)lds;
      __syncthreads();
      if (lk == 0) {
#pragma unroll
        for (int n = 0; n < 4; ++n) {
          const int c = wn * 64 + n * 16 + lr;
          sred[wm * 256 + c] = cs[n];
          sred[512 + wm * 256 + c] = cq[n];
        }
      }
      __syncthreads();
      if (t < 256) {
        atomicAdd(&osum[tn0 + t], sred[t] + sred[256 + t]);
      } else {
        const int c = t - 256;
        atomicAdd(&osq[tn0 + c], sred[512 + c] + sred[768 + c]);
      }
    }
  } else {
    const int batch = tm0 >> 11;
#pragma unroll
    for (int n = 0; n < 4; ++n) {
      const int gcol = tn0 + wn * 64 + n * 16 + lr;
      const float cb = cp[gcol];
      float mx = -3.0e38f;
#pragma unroll
      for (int m = 0; m < 8; ++m)
#pragma unroll
        for (int r = 0; r < 4; ++r)
          mx = fmaxf(mx, acc[m][n][r] + cb);
      mx = fmaxf(mx, __shfl_xor(mx, 16, 64));
      mx = fmaxf(mx, __shfl_xor(mx, 32, 64));
      if (lk == 0) {
        unsigned u = __builtin_bit_cast(unsigned, mx);
        u = (u & 0x80000000u) ? ~u : (u | 0x80000000u);
        atomicMax(&maxbuf[batch * NDIM + gcol], u);
      }
    }
  }
}

// ---------------- BN fold (one wave per output row; 512-thread blocks = 8 waves) ----------------
__device__ __forceinline__
void prep_row(const float* __restrict__ W, const float* __restrict__ g,
              const float* __restrict__ b, const float* __restrict__ c,
              const float* __restrict__ ssum, const float* __restrict__ ssq,
              int rep_stride, int nrep,
              u16* __restrict__ Wp, float* __restrict__ cp, int din, int dout,
              int bid, int t) {
  const int gw = bid * 8 + (t >> 6);
  const int l = t & 63;
  if (gw >= dout) return;
  const int o = gw;
  float acc = 0.f;
  for (int d0 = l * 4; d0 < din; d0 += 256) {
    float sm[4] = {}, sq[4] = {};
    for (int r = 0; r < nrep; ++r) {
      float4 a = *(const float4*)(ssum + (size_t)r * rep_stride + d0);
      float4 z = *(const float4*)(ssq + (size_t)r * rep_stride + d0);
      sm[0] += a.x; sm[1] += a.y; sm[2] += a.z; sm[3] += a.w;
      sq[0] += z.x; sq[1] += z.y; sq[2] += z.z; sq[3] += z.w;
    }
    float4 wv = *(const float4*)(W + (size_t)o * din + d0);
    float4 gv = *(const float4*)(g + d0);
    float4 bv = *(const float4*)(b + d0);
    float w4[4] = {wv.x, wv.y, wv.z, wv.w};
    float g4[4] = {gv.x, gv.y, gv.z, gv.w};
    float b4[4] = {bv.x, bv.y, bv.z, bv.w};
    ushort4 ov;
    u16 o4[4];
#pragma unroll
    for (int i = 0; i < 4; ++i) {
      float mean = sm[i] * INV_M;
      float var = sq[i] * INV_M - mean * mean;
      float alpha = g4[i] * rsqrtf(var + BN_EPS);
      float beta = b4[i] - mean * alpha;
      o4[i] = f2bf(w4[i] * alpha);
      acc += w4[i] * beta;
    }
    ov.x = o4[0]; ov.y = o4[1]; ov.z = o4[2]; ov.w = o4[3];
    *(ushort4*)(Wp + (size_t)o * din + d0) = ov;
  }
#pragma unroll
  for (int off = 32; off > 0; off >>= 1) acc += __shfl_xor(acc, off, 64);
  if (l == 0) cp[o] = c[o] + acc;
}

// ---------------- mega kernel: 256 blocks x 512 threads, 8 grid syncs ----------------
__global__ __launch_bounds__(512, 2)
void mega_k(const float* __restrict__ x0, const float* __restrict__ g0,
            const float* __restrict__ b0, const float* __restrict__ W0,
            const float* __restrict__ c0, const float* __restrict__ g1,
            const float* __restrict__ b1, const float* __restrict__ W1,
            const float* __restrict__ c1, const float* __restrict__ g2,
            const float* __restrict__ b2, const float* __restrict__ W2,
            const float* __restrict__ c2,
            u16* __restrict__ x0bf, u16* __restrict__ y1, u16* __restrict__ y2,
            float* __restrict__ s0rep, float* __restrict__ s1sum,
            float* __restrict__ s1sq, float* __restrict__ s2sum,
            float* __restrict__ s2sq, unsigned* __restrict__ maxbuf,
            u16* __restrict__ W0p, u16* __restrict__ W1p, u16* __restrict__ W2p,
            float* __restrict__ c0p, float* __restrict__ c1p, float* __restrict__ c2p,
            float* __restrict__ out) {
  cg::grid_group grid = cg::this_grid();
  __shared__ __align__(16) u16 lds[8 * 8192];
  const int bid = (int)blockIdx.x;
  const int t = (int)threadIdx.x;
  const int swz = (bid & 7) * 32 + (bid >> 3);  // XCD-chunked, bijective on [0,256)

  // ---- phase Z: zero stats + maxbuf (contiguous region starting at s0rep) ----
  for (int gid = bid * 512 + t; gid < ZWORDS; gid += 256 * 512)
    s0rep[gid] = 0.f;
  __threadfence();
  grid.sync();

  // ---- phase S: layer-0 stats + fp32->bf16 cast (256 rows/block) ----
  {
    const int tc = t & 63, tr = t >> 6;
    float s[4] = {}, q[4] = {};
#pragma unroll
    for (int pass = 0; pass < 4; ++pass) {
      const int rb = bid * 256 + pass * 64 + tr * 8;
      float4 v[8];
#pragma unroll
      for (int i = 0; i < 8; ++i)
        v[i] = *(const float4*)(x0 + (size_t)(rb + i) * 256 + tc * 4);
#pragma unroll
      for (int i = 0; i < 8; ++i) {
        ushort4 ov;
        ov.x = f2bf(v[i].x); ov.y = f2bf(v[i].y);
        ov.z = f2bf(v[i].z); ov.w = f2bf(v[i].w);
        *(ushort4*)(x0bf + (size_t)(rb + i) * 256 + tc * 4) = ov;
        s[0] += v[i].x; q[0] += v[i].x * v[i].x;
        s[1] += v[i].y; q[1] += v[i].y * v[i].y;
        s[2] += v[i].z; q[2] += v[i].z * v[i].z;
        s[3] += v[i].w; q[3] += v[i].w * v[i].w;
      }
    }
    float* red = (float*)lds;  // [8][256]
    float* dst = s0rep + (bid & (NREP - 1)) * 512;
#pragma unroll
    for (int i = 0; i < 4; ++i) red[tr * 256 + tc * 4 + i] = s[i];
    __syncthreads();
    if (tr == 0) {
#pragma unroll
      for (int i = 0; i < 4; ++i) {
        const int c = tc * 4 + i;
        float a = red[c] + red[256 + c] + red[512 + c] + red[768 + c] +
                  red[1024 + c] + red[1280 + c] + red[1536 + c] + red[1792 + c];
        atomicAdd(&dst[c], a);
      }
    }
    __syncthreads();
#pragma unroll
    for (int i = 0; i < 4; ++i) red[tr * 256 + tc * 4 + i] = q[i];
    __syncthreads();
    if (tr == 0) {
#pragma unroll
      for (int i = 0; i < 4; ++i) {
        const int c = tc * 4 + i;
        float a = red[c] + red[256 + c] + red[512 + c] + red[768 + c] +
                  red[1024 + c] + red[1280 + c] + red[1536 + c] + red[1792 + c];
        atomicAdd(&dst[256 + c], a);
      }
    }
    __syncthreads();
  }
  __threadfence();
  grid.sync();

  // ---- P0 ----
  prep_row(W0, g0, b0, c0, s0rep, s0rep + 256, 512, NREP, W0p, c0p, 256, 512, bid, t);
  __threadfence();
  grid.sync();

  // ---- G0: 512 tiles over 256 blocks ----
  for (int r = 0; r < 2; ++r)
    gemm_tile<256, 512, true, false>(x0bf, W0p, c0p, y1, s1sum, s1sq, nullptr,
                                     r * 256 + swz, lds, t);
  __threadfence();
  grid.sync();

  // ---- P1 ----
  prep_row(W1, g1, b1, c1, s1sum, s1sq, 0, 1, W1p, c1p, 512, 512, bid, t);
  __threadfence();
  grid.sync();

  // ---- G1 ----
  for (int r = 0; r < 2; ++r)
    gemm_tile<512, 512, true, false>(y1, W1p, c1p, y2, s2sum, s2sq, nullptr,
                                     r * 256 + swz, lds, t);
  __threadfence();
  grid.sync();

  // ---- P2 ----
  prep_row(W2, g2, b2, c2, s2sum, s2sq, 0, 1, W2p, c2p, 512, 1024, bid, t);
  __threadfence();
  grid.sync();

  // ---- G2: 1024 tiles over 256 blocks; max epilogue ----
  for (int r = 0; r < 4; ++r)
    gemm_tile<512, 1024, false, true>(y2, W2p, c2p, nullptr, nullptr, nullptr,
                                      maxbuf, r * 256 + swz, lds, t);
  __threadfence();
  grid.sync();

  // ---- D: decode ----
  {
    const int gid = bid * 512 + t;
    if (gid < 32768) {
      unsigned u = maxbuf[gid];
      u = (u & 0x80000000u) ? (u & 0x7FFFFFFFu) : ~u;
      out[gid] = __builtin_bit_cast(float, u);
    }
  }
}

extern "C" void kernel_launch(void* const* d_in, const int* in_sizes, int n_in,
                              void* d_out, int out_size, void* d_ws, size_t ws_size,
                              hipStream_t stream) {
  const float* x0 = (const float*)d_in[0];
  const float* g0 = (const float*)d_in[1];
  const float* b0 = (const float*)d_in[2];
  const float* W0 = (const float*)d_in[3];
  const float* c0 = (const float*)d_in[4];
  const float* g1 = (const float*)d_in[5];
  const float* b1 = (const float*)d_in[6];
  const float* W1 = (const float*)d_in[7];
  const float* c1 = (const float*)d_in[8];
  const float* g2 = (const float*)d_in[9];
  const float* b2 = (const float*)d_in[10];
  const float* W2 = (const float*)d_in[11];
  const float* c2 = (const float*)d_in[12];

  char* ws = (char*)d_ws;
  size_t off = 0;
  auto alloc = [&](size_t bytes) -> char* {
    char* p = ws + off;
    off += (bytes + 255) & ~(size_t)255;
    return p;
  };
  u16* x0bf = (u16*)alloc((size_t)MROWS * 256 * 2);
  u16* y1 = (u16*)alloc((size_t)MROWS * 512 * 2);
  u16* y2 = (u16*)alloc((size_t)MROWS * 512 * 2);
  float* s0rep = (float*)alloc((size_t)ZWORDS * 4);
  float* s1sum = s0rep + NREP * 512;
  float* s1sq = s1sum + 512;
  float* s2sum = s1sum + 1024;
  float* s2sq = s2sum + 512;
  unsigned* maxbuf = (unsigned*)(s1sum + 2048);
  u16* W0p = (u16*)alloc(512 * 256 * 2);
  u16* W1p = (u16*)alloc(512 * 512 * 2);
  u16* W2p = (u16*)alloc(1024 * 512 * 2);
  float* c0p = (float*)alloc(512 * 4);
  float* c1p = (float*)alloc(512 * 4);
  float* c2p = (float*)alloc(1024 * 4);
  float* outp = (float*)d_out;
  if (off > ws_size) return;

  void* args[] = {
    (void*)&x0, (void*)&g0, (void*)&b0, (void*)&W0, (void*)&c0,
    (void*)&g1, (void*)&b1, (void*)&W1, (void*)&c1,
    (void*)&g2, (void*)&b2, (void*)&W2, (void*)&c2,
    (void*)&x0bf, (void*)&y1, (void*)&y2,
    (void*)&s0rep, (void*)&s1sum, (void*)&s1sq, (void*)&s2sum, (void*)&s2sq,
    (void*)&maxbuf,
    (void*)&W0p, (void*)&W1p, (void*)&W2p,
    (void*)&c0p, (void*)&c1p, (void*)&c2p,
    (void*)&outp
  };
  hipLaunchCooperativeKernel((void*)mega_k, dim3(256), dim3(512), args, 0, stream);
}

// Round 18
// 726.842 us; speedup vs baseline: 1.0087x; 1.0087x over previous
//
#include <hip/hip_runtime.h>
#include <hip/hip_bf16.h>
#include <hip/hip_cooperative_groups.h>
#include <stdint.h>

namespace cg = cooperative_groups;

typedef unsigned short u16;
typedef __attribute__((ext_vector_type(8))) __bf16 bf16x8;
typedef __attribute__((ext_vector_type(4))) float f32x4;

#define BN_EPS 1e-5f
#define MROWS 65536
#define INV_M (1.0f / 65536.0f)
#define NREP 16
// zero region: s0rep[16*512] | s1sum/s1sq[1024] | s2sum/s2sq[1024] | maxbuf[32768]
#define ZWORDS (16 * 512 + 2048 + 32768)

__device__ __forceinline__ u16 f2bf(float f) {
  unsigned u = __builtin_bit_cast(unsigned, f);
  unsigned r = (u + 0x7FFFu + ((u >> 16) & 1u)) >> 16;
  return (u16)r;
}

#define GLDS16(gp, lp) __builtin_amdgcn_global_load_lds( \
    (__attribute__((address_space(1))) void*)(void*)(gp), \
    (__attribute__((address_space(3))) void*)(lp), 16, 0, 0)

// ---------------- GEMM tile (r13 body verbatim, tile index as parameter) ----------------
template <int KDIM, int NDIM, bool RELU, bool DOMAX>
__device__ __forceinline__
void gemm_tile(const u16* __restrict__ A, const u16* __restrict__ B,
               const float* __restrict__ cp, u16* __restrict__ Y,
               float* __restrict__ osum, float* __restrict__ osq,
               unsigned* __restrict__ maxbuf, int tile, u16* lds, int t) {
  constexpr int NK = KDIM >> 5;
  const int w = t >> 6, l = t & 63;
  const int lr = l & 15, lk = l >> 4;
  const int wm = w >> 2, wn = w & 3;
  constexpr int TILES_N = NDIM >> 8;
  const int tm0 = (tile / TILES_N) << 8;
  const int tn0 = (tile % TILES_N) << 8;

  // mega-kernel tile entry: drain vmem (epilogue stores/atomics of prior tile,
  // so prologue vmcnt(8) counts ONLY its own stages) and protect LDS reuse.
  asm volatile("s_waitcnt vmcnt(0)" ::: "memory");
  __syncthreads();

  const int srow = t >> 2;
  const int scol = (((t & 3) ^ ((t >> 3) & 3)) << 3);
  const u16* Ag = A + (size_t)(tm0 + srow) * KDIM + scol;
  const u16* Bg = B + (size_t)(tn0 + srow) * KDIM + scol;
  u16* const ldsA = lds;
  u16* const ldsB = lds + 4 * 8192;

#define STAGE_A(slot_, kt_) do { \
    GLDS16(Ag + (kt_) * 32, ldsA + (slot_) * 8192 + t * 8); \
    GLDS16(Ag + (size_t)128 * KDIM + (kt_) * 32, ldsA + (slot_) * 8192 + 4096 + t * 8); \
  } while (0)
#define STAGE_B(slot_, kt_) do { \
    GLDS16(Bg + (kt_) * 32, ldsB + (slot_) * 8192 + t * 8); \
    GLDS16(Bg + (size_t)128 * KDIM + (kt_) * 32, ldsB + (slot_) * 8192 + 4096 + t * 8); \
  } while (0)

  const int pc = (lk ^ ((lr >> 1) & 3)) * 8;
  const int rba = wm * 128 + lr;
  const int rbb = wn * 64 + lr;

  f32x4 acc[8][4] = {};

  STAGE_A(0, 0); STAGE_B(0, 0);
  STAGE_A(1, 1); STAGE_B(1, 1);
  STAGE_A(2, 2); STAGE_B(2, 2);
  asm volatile("s_waitcnt vmcnt(8)" ::: "memory");
  __builtin_amdgcn_s_barrier();

#pragma unroll
  for (int T = 0; T < NK; ++T) {
    const int sl = T & 3;
    const u16* la = ldsA + sl * 8192;
    const u16* lb = ldsB + sl * 8192;
    bf16x8 af[4], bf[4];
#pragma unroll
    for (int n = 0; n < 4; ++n)
      bf[n] = *(const bf16x8*)(lb + (rbb + n * 16) * 32 + pc);
#pragma unroll
    for (int j = 0; j < 4; ++j)
      af[j] = *(const bf16x8*)(la + (rba + j * 16) * 32 + pc);
    if (T + 3 < NK) STAGE_A((T + 3) & 3, T + 3);
    __builtin_amdgcn_s_barrier();
    __builtin_amdgcn_s_setprio(1);
#pragma unroll
    for (int j = 0; j < 4; ++j)
#pragma unroll
      for (int n = 0; n < 4; ++n)
        acc[j][n] = __builtin_amdgcn_mfma_f32_16x16x32_bf16(af[j], bf[n], acc[j][n], 0, 0, 0);
    __builtin_amdgcn_s_setprio(0);
#pragma unroll
    for (int j = 0; j < 4; ++j)
      af[j] = *(const bf16x8*)(la + (rba + 64 + j * 16) * 32 + pc);
    if (T + 3 < NK) STAGE_B((T + 3) & 3, T + 3);
    if (T < NK - 3)       asm volatile("s_waitcnt vmcnt(8)" ::: "memory");
    else if (T == NK - 3) asm volatile("s_waitcnt vmcnt(4)" ::: "memory");
    else if (T == NK - 2) asm volatile("s_waitcnt vmcnt(0)" ::: "memory");
    __builtin_amdgcn_s_barrier();
    __builtin_amdgcn_s_setprio(1);
#pragma unroll
    for (int j = 0; j < 4; ++j)
#pragma unroll
      for (int n = 0; n < 4; ++n)
        acc[4 + j][n] = __builtin_amdgcn_mfma_f32_16x16x32_bf16(af[j], bf[n], acc[4 + j][n], 0, 0, 0);
    __builtin_amdgcn_s_setprio(0);
  }
#undef STAGE_A
#undef STAGE_B

  if (!DOMAX) {
    float cs[4] = {}, cq[4] = {};
#pragma unroll
    for (int n = 0; n < 4; ++n) {
      const int gcol = tn0 + wn * 64 + n * 16 + lr;
      const float cb = cp[gcol];
#pragma unroll
      for (int m = 0; m < 8; ++m) {
        const int grow = tm0 + wm * 128 + m * 16 + lk * 4;
#pragma unroll
        for (int r = 0; r < 4; ++r) {
          float v = acc[m][n][r] + cb;
          if (RELU) v = fmaxf(v, 0.f);
          Y[(size_t)(grow + r) * NDIM + gcol] = f2bf(v);
          cs[n] += v;
          cq[n] += v * v;
        }
      }
    }
    if (RELU) {
#pragma unroll
      for (int n = 0; n < 4; ++n) {
        cs[n] += __shfl_xor(cs[n], 16, 64);
        cs[n] += __shfl_xor(cs[n], 32, 64);
        cq[n] += __shfl_xor(cq[n], 16, 64);
        cq[n] += __shfl_xor(cq[n], 32, 64);
      }
      float* sred = (float*)lds;
      __syncthreads();
      if (lk == 0) {
#pragma unroll
        for (int n = 0; n < 4; ++n) {
          const int c = wn * 64 + n * 16 + lr;
          sred[wm * 256 + c] = cs[n];
          sred[512 + wm * 256 + c] = cq[n];
        }
      }
      __syncthreads();
      if (t < 256) {
        atomicAdd(&osum[tn0 + t], sred[t] + sred[256 + t]);
      } else {
        const int c = t - 256;
        atomicAdd(&osq[tn0 + c], sred[512 + c] + sred[768 + c]);
      }
    }
  } else {
    const int batch = tm0 >> 11;
#pragma unroll
    for (int n = 0; n < 4; ++n) {
      const int gcol = tn0 + wn * 64 + n * 16 + lr;
      const float cb = cp[gcol];
      float mx = -3.0e38f;
#pragma unroll
      for (int m = 0; m < 8; ++m)
#pragma unroll
        for (int r = 0; r < 4; ++r)
          mx = fmaxf(mx, acc[m][n][r] + cb);
      mx = fmaxf(mx, __shfl_xor(mx, 16, 64));
      mx = fmaxf(mx, __shfl_xor(mx, 32, 64));
      if (lk == 0) {
        unsigned u = __builtin_bit_cast(unsigned, mx);
        u = (u & 0x80000000u) ? ~u : (u | 0x80000000u);
        atomicMax(&maxbuf[batch * NDIM + gcol], u);
      }
    }
  }
}

// ---------------- BN fold (one wave per output row; 512-thread blocks = 8 waves) ----------------
__device__ __forceinline__
void prep_row(const float* __restrict__ W, const float* __restrict__ g,
              const float* __restrict__ b, const float* __restrict__ c,
              const float* __restrict__ ssum, const float* __restrict__ ssq,
              int rep_stride, int nrep,
              u16* __restrict__ Wp, float* __restrict__ cp, int din, int dout,
              int bid, int t) {
  const int gw = bid * 8 + (t >> 6);
  const int l = t & 63;
  if (gw >= dout) return;
  const int o = gw;
  float acc = 0.f;
  for (int d0 = l * 4; d0 < din; d0 += 256) {
    float sm[4] = {}, sq[4] = {};
    for (int r = 0; r < nrep; ++r) {
      float4 a = *(const float4*)(ssum + (size_t)r * rep_stride + d0);
      float4 z = *(const float4*)(ssq + (size_t)r * rep_stride + d0);
      sm[0] += a.x; sm[1] += a.y; sm[2] += a.z; sm[3] += a.w;
      sq[0] += z.x; sq[1] += z.y; sq[2] += z.z; sq[3] += z.w;
    }
    float4 wv = *(const float4*)(W + (size_t)o * din + d0);
    float4 gv = *(const float4*)(g + d0);
    float4 bv = *(const float4*)(b + d0);
    float w4[4] = {wv.x, wv.y, wv.z, wv.w};
    float g4[4] = {gv.x, gv.y, gv.z, gv.w};
    float b4[4] = {bv.x, bv.y, bv.z, bv.w};
    ushort4 ov;
    u16 o4[4];
#pragma unroll
    for (int i = 0; i < 4; ++i) {
      float mean = sm[i] * INV_M;
      float var = sq[i] * INV_M - mean * mean;
      float alpha = g4[i] * rsqrtf(var + BN_EPS);
      float beta = b4[i] - mean * alpha;
      o4[i] = f2bf(w4[i] * alpha);
      acc += w4[i] * beta;
    }
    ov.x = o4[0]; ov.y = o4[1]; ov.z = o4[2]; ov.w = o4[3];
    *(ushort4*)(Wp + (size_t)o * din + d0) = ov;
  }
#pragma unroll
  for (int off = 32; off > 0; off >>= 1) acc += __shfl_xor(acc, off, 64);
  if (l == 0) cp[o] = c[o] + acc;
}

// ---------------- mega kernel: 256 blocks x 512 threads, 8 grid syncs ----------------
// r18: launch_bounds (512, 1) — r17's (512,2) capped the allocator at 128 VGPR
// and spilled the 128-reg accumulator to scratch (WRITE_SIZE 2MB->262MB,
// MfmaUtil 6.4%). 1 wave/EU minimum gives the full unified register budget;
// occupancy is LDS-bound to 1 block/CU regardless.
__global__ __launch_bounds__(512, 1)
void mega_k(const float* __restrict__ x0, const float* __restrict__ g0,
            const float* __restrict__ b0, const float* __restrict__ W0,
            const float* __restrict__ c0, const float* __restrict__ g1,
            const float* __restrict__ b1, const float* __restrict__ W1,
            const float* __restrict__ c1, const float* __restrict__ g2,
            const float* __restrict__ b2, const float* __restrict__ W2,
            const float* __restrict__ c2,
            u16* __restrict__ x0bf, u16* __restrict__ y1, u16* __restrict__ y2,
            float* __restrict__ s0rep, float* __restrict__ s1sum,
            float* __restrict__ s1sq, float* __restrict__ s2sum,
            float* __restrict__ s2sq, unsigned* __restrict__ maxbuf,
            u16* __restrict__ W0p, u16* __restrict__ W1p, u16* __restrict__ W2p,
            float* __restrict__ c0p, float* __restrict__ c1p, float* __restrict__ c2p,
            float* __restrict__ out) {
  cg::grid_group grid = cg::this_grid();
  __shared__ __align__(16) u16 lds[8 * 8192];
  const int bid = (int)blockIdx.x;
  const int t = (int)threadIdx.x;
  const int swz = (bid & 7) * 32 + (bid >> 3);  // XCD-chunked, bijective on [0,256)

  // ---- phase Z: zero stats + maxbuf (contiguous region starting at s0rep) ----
  for (int gid = bid * 512 + t; gid < ZWORDS; gid += 256 * 512)
    s0rep[gid] = 0.f;
  __threadfence();
  grid.sync();

  // ---- phase S: layer-0 stats + fp32->bf16 cast (256 rows/block) ----
  {
    const int tc = t & 63, tr = t >> 6;
    float s[4] = {}, q[4] = {};
#pragma unroll
    for (int pass = 0; pass < 4; ++pass) {
      const int rb = bid * 256 + pass * 64 + tr * 8;
      float4 v[8];
#pragma unroll
      for (int i = 0; i < 8; ++i)
        v[i] = *(const float4*)(x0 + (size_t)(rb + i) * 256 + tc * 4);
#pragma unroll
      for (int i = 0; i < 8; ++i) {
        ushort4 ov;
        ov.x = f2bf(v[i].x); ov.y = f2bf(v[i].y);
        ov.z = f2bf(v[i].z); ov.w = f2bf(v[i].w);
        *(ushort4*)(x0bf + (size_t)(rb + i) * 256 + tc * 4) = ov;
        s[0] += v[i].x; q[0] += v[i].x * v[i].x;
        s[1] += v[i].y; q[1] += v[i].y * v[i].y;
        s[2] += v[i].z; q[2] += v[i].z * v[i].z;
        s[3] += v[i].w; q[3] += v[i].w * v[i].w;
      }
    }
    float* red = (float*)lds;  // [8][256]
    float* dst = s0rep + (bid & (NREP - 1)) * 512;
#pragma unroll
    for (int i = 0; i < 4; ++i) red[tr * 256 + tc * 4 + i] = s[i];
    __syncthreads();
    if (tr == 0) {
#pragma unroll
      for (int i = 0; i < 4; ++i) {
        const int c = tc * 4 + i;
        float a = red[c] + red[256 + c] + red[512 + c] + red[768 + c] +
                  red[1024 + c] + red[1280 + c] + red[1536 + c] + red[1792 + c];
        atomicAdd(&dst[c], a);
      }
    }
    __syncthreads();
#pragma unroll
    for (int i = 0; i < 4; ++i) red[tr * 256 + tc * 4 + i] = q[i];
    __syncthreads();
    if (tr == 0) {
#pragma unroll
      for (int i = 0; i < 4; ++i) {
        const int c = tc * 4 + i;
        float a = red[c] + red[256 + c] + red[512 + c] + red[768 + c] +
                  red[1024 + c] + red[1280 + c] + red[1536 + c] + red[1792 + c];
        atomicAdd(&dst[256 + c], a);
      }
    }
    __syncthreads();
  }
  __threadfence();
  grid.sync();

  // ---- P0 ----
  prep_row(W0, g0, b0, c0, s0rep, s0rep + 256, 512, NREP, W0p, c0p, 256, 512, bid, t);
  __threadfence();
  grid.sync();

  // ---- G0: 512 tiles over 256 blocks ----
  for (int r = 0; r < 2; ++r)
    gemm_tile<256, 512, true, false>(x0bf, W0p, c0p, y1, s1sum, s1sq, nullptr,
                                     r * 256 + swz, lds, t);
  __threadfence();
  grid.sync();

  // ---- P1 ----
  prep_row(W1, g1, b1, c1, s1sum, s1sq, 0, 1, W1p, c1p, 512, 512, bid, t);
  __threadfence();
  grid.sync();

  // ---- G1 ----
  for (int r = 0; r < 2; ++r)
    gemm_tile<512, 512, true, false>(y1, W1p, c1p, y2, s2sum, s2sq, nullptr,
                                     r * 256 + swz, lds, t);
  __threadfence();
  grid.sync();

  // ---- P2 ----
  prep_row(W2, g2, b2, c2, s2sum, s2sq, 0, 1, W2p, c2p, 512, 1024, bid, t);
  __threadfence();
  grid.sync();

  // ---- G2: 1024 tiles over 256 blocks; max epilogue ----
  for (int r = 0; r < 4; ++r)
    gemm_tile<512, 1024, false, true>(y2, W2p, c2p, nullptr, nullptr, nullptr,
                                      maxbuf, r * 256 + swz, lds, t);
  __threadfence();
  grid.sync();

  // ---- D: decode ----
  {
    const int gid = bid * 512 + t;
    if (gid < 32768) {
      unsigned u = maxbuf[gid];
      u = (u & 0x80000000u) ? (u & 0x7FFFFFFFu) : ~u;
      out[gid] = __builtin_bit_cast(float, u);
    }
  }
}

extern "C" void kernel_launch(void* const* d_in, const int* in_sizes, int n_in,
                              void* d_out, int out_size, void* d_ws, size_t ws_size,
                              hipStream_t stream) {
  const float* x0 = (const float*)d_in[0];
  const float* g0 = (const float*)d_in[1];
  const float* b0 = (const float*)d_in[2];
  const float* W0 = (const float*)d_in[3];
  const float* c0 = (const float*)d_in[4];
  const float* g1 = (const float*)d_in[5];
  const float* b1 = (const float*)d_in[6];
  const float* W1 = (const float*)d_in[7];
  const float* c1 = (const float*)d_in[8];
  const float* g2 = (const float*)d_in[9];
  const float* b2 = (const float*)d_in[10];
  const float* W2 = (const float*)d_in[11];
  const float* c2 = (const float*)d_in[12];

  char* ws = (char*)d_ws;
  size_t off = 0;
  auto alloc = [&](size_t bytes) -> char* {
    char* p = ws + off;
    off += (bytes + 255) & ~(size_t)255;
    return p;
  };
  u16* x0bf = (u16*)alloc((size_t)MROWS * 256 * 2);
  u16* y1 = (u16*)alloc((size_t)MROWS * 512 * 2);
  u16* y2 = (u16*)alloc((size_t)MROWS * 512 * 2);
  float* s0rep = (float*)alloc((size_t)ZWORDS * 4);
  float* s1sum = s0rep + NREP * 512;
  float* s1sq = s1sum + 512;
  float* s2sum = s1sum + 1024;
  float* s2sq = s2sum + 512;
  unsigned* maxbuf = (unsigned*)(s1sum + 2048);
  u16* W0p = (u16*)alloc(512 * 256 * 2);
  u16* W1p = (u16*)alloc(512 * 512 * 2);
  u16* W2p = (u16*)alloc(1024 * 512 * 2);
  float* c0p = (float*)alloc(512 * 4);
  float* c1p = (float*)alloc(512 * 4);
  float* c2p = (float*)alloc(1024 * 4);
  float* outp = (float*)d_out;
  if (off > ws_size) return;

  void* args[] = {
    (void*)&x0, (void*)&g0, (void*)&b0, (void*)&W0, (void*)&c0,
    (void*)&g1, (void*)&b1, (void*)&W1, (void*)&c1,
    (void*)&g2, (void*)&b2, (void*)&W2, (void*)&c2,
    (void*)&x0bf, (void*)&y1, (void*)&y2,
    (void*)&s0rep, (void*)&s1sum, (void*)&s1sq, (void*)&s2sum, (void*)&s2sq,
    (void*)&maxbuf,
    (void*)&W0p, (void*)&W1p, (void*)&W2p,
    (void*)&c0p, (void*)&c1p, (void*)&c2p,
    (void*)&outp
  };
  hipLaunchCooperativeKernel((void*)mega_k, dim3(256), dim3(512), args, 0, stream);
}

// Round 19
// 200.814 us; speedup vs baseline: 3.6509x; 3.6195x over previous
//
#include <hip/hip_runtime.h>
#include <hip/hip_bf16.h>
#include <stdint.h>

typedef unsigned short u16;
typedef __attribute__((ext_vector_type(8))) __bf16 bf16x8;
typedef __attribute__((ext_vector_type(4))) float f32x4;

#define BN_EPS 1e-5f
#define MROWS 65536
#define INV_M (1.0f / 65536.0f)
#define NREP 16  // stat-buffer replication for atomic decontention

__device__ __forceinline__ u16 f2bf(float f) {
  unsigned u = __builtin_bit_cast(unsigned, f);
  unsigned r = (u + 0x7FFFu + ((u >> 16) & 1u)) >> 16;
  return (u16)r;
}
__device__ __forceinline__ float bf2f(u16 h) {
  return __builtin_bit_cast(float, (unsigned)h << 16);
}

// ------------- layer-0 stats + fp32->bf16 cast: x [65536,256] -------------
__global__ __launch_bounds__(256)
void stats_cast_k(const float* __restrict__ x, u16* __restrict__ xbf,
                  float* __restrict__ srep /* [NREP][512]: sum|sq */) {
  const int t = threadIdx.x;
  const int tc = t & 63, tr = t >> 6;
  const int rb = blockIdx.x * 32 + tr * 8;
  float4 v[8];
#pragma unroll
  for (int i = 0; i < 8; ++i)
    v[i] = *(const float4*)(x + (size_t)(rb + i) * 256 + tc * 4);
  float s0 = 0, s1 = 0, s2 = 0, s3 = 0, q0 = 0, q1 = 0, q2 = 0, q3 = 0;
#pragma unroll
  for (int i = 0; i < 8; ++i) {
    ushort4 ov;
    ov.x = f2bf(v[i].x); ov.y = f2bf(v[i].y);
    ov.z = f2bf(v[i].z); ov.w = f2bf(v[i].w);
    *(ushort4*)(xbf + (size_t)(rb + i) * 256 + tc * 4) = ov;
    s0 += v[i].x; q0 += v[i].x * v[i].x;
    s1 += v[i].y; q1 += v[i].y * v[i].y;
    s2 += v[i].z; q2 += v[i].z * v[i].z;
    s3 += v[i].w; q3 += v[i].w * v[i].w;
  }
  __shared__ float red[4][256];
  red[tr][tc * 4 + 0] = s0; red[tr][tc * 4 + 1] = s1;
  red[tr][tc * 4 + 2] = s2; red[tr][tc * 4 + 3] = s3;
  __syncthreads();
  float* dst = srep + (blockIdx.x & (NREP - 1)) * 512;
  if (tr == 0) {
#pragma unroll
    for (int i = 0; i < 4; ++i) {
      int c = tc * 4 + i;
      atomicAdd(&dst[c], red[0][c] + red[1][c] + red[2][c] + red[3][c]);
    }
  }
  __syncthreads();
  red[tr][tc * 4 + 0] = q0; red[tr][tc * 4 + 1] = q1;
  red[tr][tc * 4 + 2] = q2; red[tr][tc * 4 + 3] = q3;
  __syncthreads();
  if (tr == 0) {
#pragma unroll
    for (int i = 0; i < 4; ++i) {
      int c = tc * 4 + i;
      atomicAdd(&dst[256 + c], red[0][c] + red[1][c] + red[2][c] + red[3][c]);
    }
  }
}

// ------------- fold BN into weights: one WAVE per output row, float4 loads -------------
__global__ __launch_bounds__(256)
void prep_w_k(const float* __restrict__ W, const float* __restrict__ g,
              const float* __restrict__ b, const float* __restrict__ c,
              const float* __restrict__ ssum, const float* __restrict__ ssq,
              int rep_stride, int nrep,
              u16* __restrict__ Wp, float* __restrict__ cp, int din, int dout) {
  const int gw = (blockIdx.x * 256 + threadIdx.x) >> 6;  // global wave = row
  const int l = threadIdx.x & 63;
  if (gw >= dout) return;
  const int o = gw;
  float acc = 0.f;
  for (int d0 = l * 4; d0 < din; d0 += 256) {
    float sm[4] = {}, sq[4] = {};
    for (int r = 0; r < nrep; ++r) {
      float4 a = *(const float4*)(ssum + (size_t)r * rep_stride + d0);
      float4 z = *(const float4*)(ssq + (size_t)r * rep_stride + d0);
      sm[0] += a.x; sm[1] += a.y; sm[2] += a.z; sm[3] += a.w;
      sq[0] += z.x; sq[1] += z.y; sq[2] += z.z; sq[3] += z.w;
    }
    float4 wv = *(const float4*)(W + (size_t)o * din + d0);
    float4 gv = *(const float4*)(g + d0);
    float4 bv = *(const float4*)(b + d0);
    float w4[4] = {wv.x, wv.y, wv.z, wv.w};
    float g4[4] = {gv.x, gv.y, gv.z, gv.w};
    float b4[4] = {bv.x, bv.y, bv.z, bv.w};
    ushort4 ov;
    u16 o4[4];
#pragma unroll
    for (int i = 0; i < 4; ++i) {
      float mean = sm[i] * INV_M;
      float var = sq[i] * INV_M - mean * mean;
      float alpha = g4[i] * rsqrtf(var + BN_EPS);
      float beta = b4[i] - mean * alpha;
      o4[i] = f2bf(w4[i] * alpha);
      acc += w4[i] * beta;
    }
    ov.x = o4[0]; ov.y = o4[1]; ov.z = o4[2]; ov.w = o4[3];
    *(ushort4*)(Wp + (size_t)o * din + d0) = ov;
  }
#pragma unroll
  for (int off = 32; off > 0; off >>= 1) acc += __shfl_xor(acc, off, 64);
  if (l == 0) cp[o] = c[o] + acc;
}

// ------------- GEMM: Y = act(A @ B^T + c'), 256x256 tile, BK=32, ring-4 LDS -------------
// The verified local optimum (l2 62.8us, 1092 TF, MfmaUtil 45%, conflict 0).
// Ring-4 both matrices, lead-3 staging, counted boundary vmcnt(8) (never 0
// mid-loop), leading barrier + setprio clusters, both-sides LDS swizzle
// slot^=(row>>1)&3, full compile-time unroll. Experiments r6/r7/r9/r10/r12/
// r14/r15 (schedule), r11 (32x32 shape), r17/r18 (cooperative mega-kernel)
// all regressed or broke vs this. Key lessons: vmcnt is per-wave (barrier is
// the only cross-wave staging guarantee); the 128-reg accumulator walls
// occupancy at 1 block/CU and spills any larger fused kernel.
#define GLDS16(gp, lp) __builtin_amdgcn_global_load_lds( \
    (__attribute__((address_space(1))) void*)(void*)(gp), \
    (__attribute__((address_space(3))) void*)(lp), 16, 0, 0)

template <int KDIM, int NDIM, bool RELU, bool DOMAX>
__device__ __forceinline__
void gemm_body(const u16* __restrict__ A, const u16* __restrict__ B,
               const float* __restrict__ cp, u16* __restrict__ Y,
               float* __restrict__ osum, float* __restrict__ osq,
               unsigned* __restrict__ maxbuf) {
  constexpr int NK = KDIM >> 5;  // K-tiles (8 or 16)
  // ring4: A slots [4][8192] u16, then B slots [4][8192] u16  => 128 KiB
  __shared__ __align__(16) u16 lds[8 * 8192];
  const int t = threadIdx.x;
  const int w = t >> 6, l = t & 63;
  const int lr = l & 15, lk = l >> 4;
  const int wm = w >> 2, wn = w & 3;

  // XCD-aware bijective swizzle (gridDim.x % 8 == 0 for all launches here)
  const int cpx = (int)gridDim.x >> 3;
  int bid = (int)blockIdx.x;
  bid = (bid & 7) * cpx + (bid >> 3);
  constexpr int TILES_N = NDIM >> 8;
  const int tm0 = (bid / TILES_N) << 8;
  const int tn0 = (bid % TILES_N) << 8;

  // staging: tile = 256 rows x 32 u16 (16 KB), 1024 16B segs; thread t owns segs
  // t, t+512. Physical seg t -> row t>>2, slot t&3. Source slot = (t&3)^((t>>3)&3).
  const int srow = t >> 2;
  const int scol = (((t & 3) ^ ((t >> 3) & 3)) << 3);  // u16 units
  const u16* Ag = A + (size_t)(tm0 + srow) * KDIM + scol;
  const u16* Bg = B + (size_t)(tn0 + srow) * KDIM + scol;
  u16* const ldsA = lds;
  u16* const ldsB = lds + 4 * 8192;

#define STAGE_A(slot_, kt_) do { \
    GLDS16(Ag + (kt_) * 32, ldsA + (slot_) * 8192 + t * 8); \
    GLDS16(Ag + (size_t)128 * KDIM + (kt_) * 32, ldsA + (slot_) * 8192 + 4096 + t * 8); \
  } while (0)
#define STAGE_B(slot_, kt_) do { \
    GLDS16(Bg + (kt_) * 32, ldsB + (slot_) * 8192 + t * 8); \
    GLDS16(Bg + (size_t)128 * KDIM + (kt_) * 32, ldsB + (slot_) * 8192 + 4096 + t * 8); \
  } while (0)

  // ds_read: row (base + frag*16 + lr), swizzled k-slot: pc u16 = (lk ^ ((lr>>1)&3))*8
  const int pc = (lk ^ ((lr >> 1) & 3)) * 8;
  const int rba = wm * 128 + lr;  // A row base
  const int rbb = wn * 64 + lr;   // B row base

  f32x4 acc[8][4] = {};

  // prologue: stage tiles 0,1,2 (lead = 3)
  STAGE_A(0, 0); STAGE_B(0, 0);
  STAGE_A(1, 1); STAGE_B(1, 1);
  STAGE_A(2, 2); STAGE_B(2, 2);
  asm volatile("s_waitcnt vmcnt(8)" ::: "memory");  // tile 0 landed
  __builtin_amdgcn_s_barrier();

#pragma unroll
  for (int T = 0; T < NK; ++T) {
    const int sl = T & 3;  // compile-time after unroll
    const u16* la = ldsA + sl * 8192;
    const u16* lb = ldsB + sl * 8192;
    bf16x8 af[4], bf[4];
    // ---- phase 0: B frags (all 4) + A frags m=0..3 || stage A(T+3) ----
#pragma unroll
    for (int n = 0; n < 4; ++n)
      bf[n] = *(const bf16x8*)(lb + (rbb + n * 16) * 32 + pc);
#pragma unroll
    for (int j = 0; j < 4; ++j)
      af[j] = *(const bf16x8*)(la + (rba + j * 16) * 32 + pc);
    if (T + 3 < NK) STAGE_A((T + 3) & 3, T + 3);
    __builtin_amdgcn_s_barrier();
    __builtin_amdgcn_s_setprio(1);
#pragma unroll
    for (int j = 0; j < 4; ++j)
#pragma unroll
      for (int n = 0; n < 4; ++n)
        acc[j][n] = __builtin_amdgcn_mfma_f32_16x16x32_bf16(af[j], bf[n], acc[j][n], 0, 0, 0);
    __builtin_amdgcn_s_setprio(0);
    // ---- phase 1: A frags m=4..7 (B reused in regs) || stage B(T+3) ----
#pragma unroll
    for (int j = 0; j < 4; ++j)
      af[j] = *(const bf16x8*)(la + (rba + 64 + j * 16) * 32 + pc);
    if (T + 3 < NK) STAGE_B((T + 3) & 3, T + 3);
    // K-tile boundary wait: counted, never 0 mid-loop (constants after unroll).
    if (T < NK - 3)       asm volatile("s_waitcnt vmcnt(8)" ::: "memory");
    else if (T == NK - 3) asm volatile("s_waitcnt vmcnt(4)" ::: "memory");
    else if (T == NK - 2) asm volatile("s_waitcnt vmcnt(0)" ::: "memory");
    __builtin_amdgcn_s_barrier();
    __builtin_amdgcn_s_setprio(1);
#pragma unroll
    for (int j = 0; j < 4; ++j)
#pragma unroll
      for (int n = 0; n < 4; ++n)
        acc[4 + j][n] = __builtin_amdgcn_mfma_f32_16x16x32_bf16(af[j], bf[n], acc[4 + j][n], 0, 0, 0);
    __builtin_amdgcn_s_setprio(0);
  }
#undef STAGE_A
#undef STAGE_B

  if (!DOMAX) {
    float cs[4] = {}, cq[4] = {};
#pragma unroll
    for (int n = 0; n < 4; ++n) {
      const int gcol = tn0 + wn * 64 + n * 16 + lr;
      const float cb = cp[gcol];
#pragma unroll
      for (int m = 0; m < 8; ++m) {
        const int grow = tm0 + wm * 128 + m * 16 + lk * 4;
#pragma unroll
        for (int r = 0; r < 4; ++r) {
          float v = acc[m][n][r] + cb;
          if (RELU) v = fmaxf(v, 0.f);
          Y[(size_t)(grow + r) * NDIM + gcol] = f2bf(v);
          cs[n] += v;
          cq[n] += v * v;
        }
      }
    }
    if (RELU) {
#pragma unroll
      for (int n = 0; n < 4; ++n) {
        cs[n] += __shfl_xor(cs[n], 16, 64);
        cs[n] += __shfl_xor(cs[n], 32, 64);
        cq[n] += __shfl_xor(cq[n], 16, 64);
        cq[n] += __shfl_xor(cq[n], 32, 64);
      }
      float* sred = (float*)lds;  // [wm][256] sum | +512: [wm][256] sq
      __syncthreads();
      if (lk == 0) {
#pragma unroll
        for (int n = 0; n < 4; ++n) {
          const int c = wn * 64 + n * 16 + lr;
          sred[wm * 256 + c] = cs[n];
          sred[512 + wm * 256 + c] = cq[n];
        }
      }
      __syncthreads();
      if (t < 256) {
        atomicAdd(&osum[tn0 + t], sred[t] + sred[256 + t]);
      } else {
        const int c = t - 256;
        atomicAdd(&osq[tn0 + c], sred[512 + c] + sred[768 + c]);
      }
    }
  } else {
    // max-over-set epilogue: tile fully inside one batch (2048 % 256 == 0)
    const int batch = tm0 >> 11;
#pragma unroll
    for (int n = 0; n < 4; ++n) {
      const int gcol = tn0 + wn * 64 + n * 16 + lr;
      const float cb = cp[gcol];
      float mx = -3.0e38f;
#pragma unroll
      for (int m = 0; m < 8; ++m)
#pragma unroll
        for (int r = 0; r < 4; ++r)
          mx = fmaxf(mx, acc[m][n][r] + cb);
      mx = fmaxf(mx, __shfl_xor(mx, 16, 64));
      mx = fmaxf(mx, __shfl_xor(mx, 32, 64));
      if (lk == 0) {
        unsigned u = __builtin_bit_cast(unsigned, mx);
        u = (u & 0x80000000u) ? ~u : (u | 0x80000000u);
        atomicMax(&maxbuf[batch * NDIM + gcol], u);
      }
    }
  }
}

// distinct names per layer for clean profile attribution
__global__ __launch_bounds__(512, 2)
void gemm_l0(const u16* __restrict__ A, const u16* __restrict__ B,
             const float* __restrict__ cp, u16* __restrict__ Y,
             float* __restrict__ osum, float* __restrict__ osq) {
  gemm_body<256, 512, true, false>(A, B, cp, Y, osum, osq, nullptr);
}
__global__ __launch_bounds__(512, 2)
void gemm_l1(const u16* __restrict__ A, const u16* __restrict__ B,
             const float* __restrict__ cp, u16* __restrict__ Y,
             float* __restrict__ osum, float* __restrict__ osq) {
  gemm_body<512, 512, true, false>(A, B, cp, Y, osum, osq, nullptr);
}
__global__ __launch_bounds__(512, 2)
void gemm_l2(const u16* __restrict__ A, const u16* __restrict__ B,
             const float* __restrict__ cp, unsigned* __restrict__ maxbuf) {
  gemm_body<512, 1024, false, true>(A, B, cp, nullptr, nullptr, nullptr, maxbuf);
}

__global__ void decode_k(const unsigned* __restrict__ mb, float* __restrict__ out, int n) {
  int i = blockIdx.x * 256 + threadIdx.x;
  if (i < n) {
    unsigned u = mb[i];
    u = (u & 0x80000000u) ? (u & 0x7FFFFFFFu) : ~u;
    out[i] = __builtin_bit_cast(float, u);
  }
}

extern "C" void kernel_launch(void* const* d_in, const int* in_sizes, int n_in,
                              void* d_out, int out_size, void* d_ws, size_t ws_size,
                              hipStream_t stream) {
  const float* x0 = (const float*)d_in[0];
  const float* g0 = (const float*)d_in[1];
  const float* b0 = (const float*)d_in[2];
  const float* W0 = (const float*)d_in[3];
  const float* c0 = (const float*)d_in[4];
  const float* g1 = (const float*)d_in[5];
  const float* b1 = (const float*)d_in[6];
  const float* W1 = (const float*)d_in[7];
  const float* c1 = (const float*)d_in[8];
  const float* g2 = (const float*)d_in[9];
  const float* b2 = (const float*)d_in[10];
  const float* W2 = (const float*)d_in[11];
  const float* c2 = (const float*)d_in[12];

  char* ws = (char*)d_ws;
  size_t off = 0;
  auto alloc = [&](size_t bytes) -> char* {
    char* p = ws + off;
    off += (bytes + 255) & ~(size_t)255;
    return p;
  };
  u16* x0bf = (u16*)alloc((size_t)MROWS * 256 * 2);
  u16* y1 = (u16*)alloc((size_t)MROWS * 512 * 2);
  u16* y2 = (u16*)alloc((size_t)MROWS * 512 * 2);
  // contiguous zero-init region: s0 replicas [NREP][512] | stats1 | stats2 | maxbuf
  float* s0rep = (float*)alloc((NREP * 512 + 1024 + 1024 + 32768) * 4);
  float* s1sum = s0rep + NREP * 512;
  float* s1sq = s1sum + 512;
  float* s2sum = s1sum + 1024;
  float* s2sq = s2sum + 512;
  unsigned* maxbuf = (unsigned*)(s1sum + 2048);
  const size_t zbytes = (size_t)(NREP * 512 + 2048 + 32768) * 4;
  u16* W0p = (u16*)alloc(512 * 256 * 2);
  u16* W1p = (u16*)alloc(512 * 512 * 2);
  u16* W2p = (u16*)alloc(1024 * 512 * 2);
  float* c0p = (float*)alloc(512 * 4);
  float* c1p = (float*)alloc(512 * 4);
  float* c2p = (float*)alloc(1024 * 4);
  if (off > ws_size) return;

  hipMemsetAsync(s0rep, 0, zbytes, stream);

  // layer 0 (epilogue produces layer-1 BN stats)
  stats_cast_k<<<2048, 256, 0, stream>>>(x0, x0bf, s0rep);
  prep_w_k<<<128, 256, 0, stream>>>(W0, g0, b0, c0, s0rep, s0rep + 256, 512, NREP,
                                    W0p, c0p, 256, 512);
  gemm_l0<<<512, 512, 0, stream>>>(x0bf, W0p, c0p, y1, s1sum, s1sq);
  // layer 1 (epilogue produces layer-2 BN stats)
  prep_w_k<<<128, 256, 0, stream>>>(W1, g1, b1, c1, s1sum, s1sq, 0, 1,
                                    W1p, c1p, 512, 512);
  gemm_l1<<<512, 512, 0, stream>>>(y1, W1p, c1p, y2, s2sum, s2sq);
  // layer 2 + max reduction
  prep_w_k<<<256, 256, 0, stream>>>(W2, g2, b2, c2, s2sum, s2sq, 0, 1,
                                    W2p, c2p, 512, 1024);
  gemm_l2<<<1024, 512, 0, stream>>>(y2, W2p, c2p, maxbuf);
  decode_k<<<128, 256, 0, stream>>>(maxbuf, (float*)d_out, 32768);
}